// Round 1
// baseline (13.684 us; speedup 1.0000x reference)
//
#include <hip/hip_runtime.h>

#define NN 16
#define DD 65536
#define DD4 (DD / 4)        // 16384 float4 per row
#define NPAIR 120           // 16*15/2
#define NCHUNK 8
#define CHUNK4 (DD4 / NCHUNK) // 2048 float4 per chunk
#define EPS 0.01f
#define NITERS 100
#define THRESH 0.1f

// ---- Kernel 1: partial sums of squared differences for each unordered pair ----
// grid = NPAIR * NCHUNK blocks; block b handles pair (b>>3), chunk (b&7).
__global__ __launch_bounds__(256) void sumsq_pairs_kernel(
    const float* __restrict__ x, float* __restrict__ partial) {
    int b = blockIdx.x;
    int pair = b >> 3;
    int chunk = b & 7;
    // map pair index -> (i, j) with i < j
    int i = 0, p = pair;
    while (p >= 15 - i) { p -= 15 - i; ++i; }
    int j = i + 1 + p;

    const float4* xi = (const float4*)(x + (size_t)i * DD);
    const float4* xj = (const float4*)(x + (size_t)j * DD);

    int base = chunk * CHUNK4;
    float acc = 0.0f;
    #pragma unroll 4
    for (int k = base + threadIdx.x; k < base + CHUNK4; k += 256) {
        float4 a = xi[k];
        float4 c = xj[k];
        float d0 = a.x - c.x, d1 = a.y - c.y, d2 = a.z - c.z, d3 = a.w - c.w;
        acc += d0 * d0 + d1 * d1 + d2 * d2 + d3 * d3;
    }
    // full-wave (64-lane) butterfly reduce
    #pragma unroll
    for (int m = 32; m >= 1; m >>= 1) acc += __shfl_xor(acc, m, 64);

    __shared__ float sred[4];
    int lane = threadIdx.x & 63;
    int wv = threadIdx.x >> 6;
    if (lane == 0) sred[wv] = acc;
    __syncthreads();
    if (threadIdx.x == 0)
        partial[b] = ((sred[0] + sred[1]) + sred[2]) + sred[3];
}

// ---- Kernel 2: assemble C, run Sinkhorn iterations, write final loss ----
// single block, 256 threads (one per C entry).
__global__ __launch_bounds__(256) void sinkhorn_kernel(
    const float* __restrict__ partial, float* __restrict__ out) {
    __shared__ float sC[NN * 17];   // stride 17 to avoid bank conflicts on column reads
    __shared__ float su[NN], sv[NN], su_new[NN], sv_new[NN], sdu[NN];
    __shared__ float serr;
    __shared__ float sred[4];

    int tid = threadIdx.x;

    if (tid < NN) {
        su[tid] = 0.0f;
        sv[tid] = 0.0f;
        sC[tid * 17 + tid] = 0.0f;   // diagonal is exactly zero
    }
    if (tid < NPAIR) {
        int i = 0, p = tid;
        while (p >= 15 - i) { p -= 15 - i; ++i; }
        int j = i + 1 + p;
        float s = 0.0f;
        #pragma unroll
        for (int c = 0; c < NCHUNK; ++c) s += partial[tid * NCHUNK + c];
        sC[i * 17 + j] = s;
        sC[j * 17 + i] = s;
    }
    __syncthreads();

    const float log_mu = logf(1.0f / 16.0f);   // == log_nu

    // row layout: thread = (i_r, j_r); 16-lane groups share a row
    int i_r = tid >> 4, j_r = tid & 15;
    // col layout: thread = (i_c, j_c); 16-lane groups share a column
    int i_c = tid & 15, j_c = tid >> 4;

    for (int it = 0; it < NITERS; ++it) {
        // ---- u-update: lse over rows of M(u, v) ----
        float e = expf((-sC[i_r * 17 + j_r] + su[i_r] + sv[j_r]) / EPS);
        e += __shfl_xor(e, 1, 64);
        e += __shfl_xor(e, 2, 64);
        e += __shfl_xor(e, 4, 64);
        e += __shfl_xor(e, 8, 64);
        if (j_r == 0) {
            float lse = logf(e + 1e-6f);
            float un = EPS * (log_mu - lse) + su[i_r];
            su_new[i_r] = un;
            sdu[i_r] = fabsf(un - su[i_r]);
        }
        __syncthreads();

        // ---- v-update: lse over columns of M(u_new, v) ----
        float e2 = expf((-sC[i_c * 17 + j_c] + su_new[i_c] + sv[j_c]) / EPS);
        e2 += __shfl_xor(e2, 1, 64);
        e2 += __shfl_xor(e2, 2, 64);
        e2 += __shfl_xor(e2, 4, 64);
        e2 += __shfl_xor(e2, 8, 64);
        if (i_c == 0) {
            float lse = logf(e2 + 1e-6f);
            sv_new[j_c] = EPS * (log_mu - lse) + sv[j_c];
        }
        __syncthreads();

        // ---- apply update, compute err, decide on early freeze ----
        if (tid == 0) {
            float err = 0.0f;
            #pragma unroll
            for (int k = 0; k < NN; ++k) err += sdu[k];
            serr = err;
        }
        if (tid < NN) {
            su[tid] = su_new[tid];
            sv[tid] = sv_new[tid];
        }
        __syncthreads();
        // Reference freezes (u,v) once err < THRESH (after applying this
        // iteration's update) -> breaking here is exactly equivalent.
        if (serr < THRESH) break;
    }

    // ---- loss = sum(pi * C), pi = exp(M(u, v)) ----
    float c = sC[i_r * 17 + j_r];
    float term = expf((-c + su[i_r] + sv[j_r]) / EPS) * c;
    #pragma unroll
    for (int m = 32; m >= 1; m >>= 1) term += __shfl_xor(term, m, 64);
    if ((tid & 63) == 0) sred[tid >> 6] = term;
    __syncthreads();
    if (tid == 0)
        out[0] = 10.0f * (((sred[0] + sred[1]) + sred[2]) + sred[3]);
}

extern "C" void kernel_launch(void* const* d_in, const int* in_sizes, int n_in,
                              void* d_out, int out_size, void* d_ws, size_t ws_size,
                              hipStream_t stream) {
    const float* preds_S = (const float*)d_in[0];
    // preds_T (d_in[1]) is unused by the reference.
    float* partial = (float*)d_ws;          // NPAIR * NCHUNK = 960 floats
    float* out = (float*)d_out;

    hipLaunchKernelGGL(sumsq_pairs_kernel, dim3(NPAIR * NCHUNK), dim3(256), 0, stream,
                       preds_S, partial);
    hipLaunchKernelGGL(sinkhorn_kernel, dim3(1), dim3(256), 0, stream,
                       partial, out);
}